// Round 1
// baseline (2413.689 us; speedup 1.0000x reference)
//
#include <hip/hip_runtime.h>
#include <hip/hip_bf16.h>
#include <stdint.h>

#define N_ 2048
#define D_ 2048
#define C_ 50257
#define CP 50304   // 393*128, zero-padded class dim (divisible by 128 and 32)

typedef __attribute__((ext_vector_type(8))) short bf16x8;
typedef __attribute__((ext_vector_type(4))) float floatx4;

static __device__ __forceinline__ unsigned short f2bf(float f) {
    union { __hip_bfloat16 h; unsigned short u; } v;
    v.h = __float2bfloat16(f);
    return v.u;
}

// async global->LDS, 16B per lane, wave-uniform LDS base + lane*16
static __device__ __forceinline__ void gl_lds16(const void* g, void* l) {
    __builtin_amdgcn_global_load_lds(
        (const __attribute__((address_space(1))) unsigned int*)g,
        (__attribute__((address_space(3))) unsigned int*)l,
        16, 0, 0);
}

// ---------------- convert x (fp32 -> bf16), N*D elements ----------------
__global__ void k_convert_x(const float* __restrict__ x, unsigned short* __restrict__ xb) {
    int i = blockIdx.x * 256 + threadIdx.x;          // one thread per 4 elems
    float4 v = ((const float4*)x)[i];
    ushort4 o;
    o.x = f2bf(v.x); o.y = f2bf(v.y); o.z = f2bf(v.z); o.w = f2bf(v.w);
    ((ushort4*)xb)[i] = o;
}

// ------------- convert W: Wb[D][CP] bf16 and WbT[CP][D] bf16 -------------
__global__ void k_convert_w(const float* __restrict__ W,
                            unsigned short* __restrict__ Wb,
                            unsigned short* __restrict__ WbT) {
    __shared__ float tile[64][65];
    const int c0 = blockIdx.x * 64;   // class dim (padded range)
    const int d0 = blockIdx.y * 64;   // feature dim
    const int t = threadIdx.x;
    #pragma unroll
    for (int i = 0; i < 16; ++i) {
        int e = t + i * 256;
        int r = e >> 6, cc = e & 63;
        int c = c0 + cc;
        float v = (c < C_) ? W[(size_t)(d0 + r) * C_ + c] : 0.f;
        tile[r][cc] = v;
        Wb[(size_t)(d0 + r) * CP + c0 + cc] = f2bf(v);
    }
    __syncthreads();
    #pragma unroll
    for (int i = 0; i < 16; ++i) {
        int e = t + i * 256;
        int r = e >> 6, cc = e & 63;  // r: c-offset, cc: d-offset
        WbT[(size_t)(c0 + r) * D_ + d0 + cc] = f2bf(tile[cc][r]);
    }
}

// ---------------- BT-GEMM: Cout[m,n] (+)= sum_k A[m,k]*BT[n,k] ----------------
// A [M][lda] bf16 k-contig; BT [Nd][ldb] bf16 k-contig; Cout fp32 [M][ldc].
// 128x128 tile, BK=32, 256 threads = 4 waves in 2x2, 16x16x32 bf16 MFMA.
__global__ __launch_bounds__(256, 3) void k_gemm_bt(
    const unsigned short* __restrict__ A, const unsigned short* __restrict__ BT,
    float* __restrict__ Cout, const float* __restrict__ bias,
    int lda, int ldb, int ldc, int nStore, int kIters, int kChunk, int useAtomic)
{
    __shared__ unsigned short sA[128 * 32];
    __shared__ unsigned short sB[128 * 32];
    const int tid  = threadIdx.x;
    const int wave = tid >> 6;
    const int lane = tid & 63;
    const int bm = blockIdx.x, bn = blockIdx.y;

    // staging: 16 chunks of 1KB (16 rows x 32 bf16); wave w owns A-chunks {2w,2w+1}, B same
    const int ca0 = wave * 2;
    const unsigned short* gA0 = A  + (size_t)(bm * 128 + ca0 * 16 + (lane >> 2)) * lda + (lane & 3) * 8;
    const unsigned short* gA1 = gA0 + (size_t)16 * lda;
    const unsigned short* gB0 = BT + (size_t)(bn * 128 + ca0 * 16 + (lane >> 2)) * ldb + (lane & 3) * 8;
    const unsigned short* gB1 = gB0 + (size_t)16 * ldb;
    unsigned short* lA0 = sA + ca0 * 512;
    unsigned short* lA1 = lA0 + 512;
    unsigned short* lB0 = sB + ca0 * 512;
    unsigned short* lB1 = lB0 + 512;

    const int rm = (wave >> 1) * 64;  // wave row quadrant
    const int cn = (wave & 1) * 64;   // wave col quadrant
    const int fr = lane & 15;
    const int fq = lane >> 4;

    floatx4 acc[4][4] = {};

    int it0 = blockIdx.z * kChunk;
    int it1 = it0 + kChunk; if (it1 > kIters) it1 = kIters;

    for (int it = it0; it < it1; ++it) {
        const size_t kk = (size_t)it * 32;
        gl_lds16(gA0 + kk, lA0);
        gl_lds16(gA1 + kk, lA1);
        gl_lds16(gB0 + kk, lB0);
        gl_lds16(gB1 + kk, lB1);
        __syncthreads();   // vmcnt(0) drain + barrier

        bf16x8 af[4], bfr[4];
        #pragma unroll
        for (int r = 0; r < 4; ++r)
            af[r] = *(const bf16x8*)(sA + (rm + r * 16 + fr) * 32 + fq * 8);
        #pragma unroll
        for (int c = 0; c < 4; ++c)
            bfr[c] = *(const bf16x8*)(sB + (cn + c * 16 + fr) * 32 + fq * 8);
        #pragma unroll
        for (int r = 0; r < 4; ++r)
            #pragma unroll
            for (int c = 0; c < 4; ++c)
                acc[r][c] = __builtin_amdgcn_mfma_f32_16x16x32_bf16(af[r], bfr[c], acc[r][c], 0, 0, 0);
        __syncthreads();   // protect LDS from next iter's staging
    }

    // epilogue: C/D layout col = lane&15, row = (lane>>4)*4 + i
    #pragma unroll
    for (int c = 0; c < 4; ++c) {
        const int gcol = bn * 128 + cn + c * 16 + fr;
        if (gcol >= nStore) continue;
        const float bv = bias ? bias[gcol] : 0.f;
        #pragma unroll
        for (int r = 0; r < 4; ++r) {
            #pragma unroll
            for (int i = 0; i < 4; ++i) {
                const int grow = bm * 128 + rm + r * 16 + fq * 4 + i;
                float v = acc[r][c][i] + bv;
                if (useAtomic) atomicAdd(&Cout[(size_t)grow * ldc + gcol], v);
                else           Cout[(size_t)grow * ldc + gcol] = v;
            }
        }
    }
}

// ------------- per-row: m_n (max), l_n (sumexp), s_n (sum y); stats = {m, s/l} -------------
__global__ void k_rowstats(const float* __restrict__ logits, const float* __restrict__ y,
                           float* __restrict__ stats) {
    const int n = blockIdx.x;
    const int t = threadIdx.x;
    const float* lrow = logits + (size_t)n * C_;
    const float* yrow = y + (size_t)n * C_;
    float m = -3.4e38f, l = 0.f, s = 0.f;
    for (int c = t; c < C_; c += 256) {
        float v = lrow[c];
        s += yrow[c];
        float mn = fmaxf(m, v);
        l = l * __expf(m - mn) + __expf(v - mn);
        m = mn;
    }
    __shared__ float sm[256], sl[256], ss[256];
    sm[t] = m; sl[t] = l; ss[t] = s;
    __syncthreads();
    for (int o = 128; o > 0; o >>= 1) {
        if (t < o) {
            float m2 = sm[t + o], l2 = sl[t + o];
            float mo = fmaxf(sm[t], m2);
            sl[t] = sl[t] * __expf(sm[t] - mo) + l2 * __expf(m2 - mo);
            sm[t] = mo;
            ss[t] += ss[t + o];
        }
        __syncthreads();
    }
    if (t == 0) {
        stats[2 * n]     = sm[0];
        stats[2 * n + 1] = ss[0] / sl[0];   // a_n = s_n / l_n
    }
}

// ------------- G[n,c] = a_n*exp(logit-m_n) - y[n,c]  (bf16, padded cols = 0) -------------
__global__ void k_gmat(const float* __restrict__ logits, const float* __restrict__ y,
                       const float* __restrict__ stats, unsigned short* __restrict__ Gb) {
    const int tid = blockIdx.x * 256 + threadIdx.x;  // one per 4 padded elems
    const int perRow = CP / 4;                       // 12576
    const int n = tid / perRow;
    const int j = tid - n * perRow;
    const int c0 = j * 4;
    const float m = stats[2 * n], a = stats[2 * n + 1];
    const float* lrow = logits + (size_t)n * C_;
    const float* yrow = y + (size_t)n * C_;
    ushort4 o;
    unsigned short g[4];
    #pragma unroll
    for (int i = 0; i < 4; ++i) {
        int c = c0 + i;
        float gv = 0.f;
        if (c < C_) gv = a * __expf(lrow[c] - m) - yrow[c];
        g[i] = f2bf(gv);
    }
    o.x = g[0]; o.y = g[1]; o.z = g[2]; o.w = g[3];
    ((ushort4*)(Gb + (size_t)n * CP))[j] = o;
}

extern "C" void kernel_launch(void* const* d_in, const int* in_sizes, int n_in,
                              void* d_out, int out_size, void* d_ws, size_t ws_size,
                              hipStream_t stream) {
    const float* x = (const float*)d_in[0];
    const float* y = (const float*)d_in[1];
    const float* W = (const float*)d_in[2];
    const float* b = (const float*)d_in[3];

    float* dx     = (float*)d_out;                 // [N][D]
    float* logits = dx + (size_t)N_ * D_;          // [N][C]

    // workspace layout (~627 MB)
    unsigned short* xb  = (unsigned short*)d_ws;               // N*D
    unsigned short* Wb  = xb  + (size_t)N_ * D_;               // D*CP
    unsigned short* WbT = Wb  + (size_t)D_ * CP;               // CP*D
    unsigned short* Gb  = WbT + (size_t)CP * D_;               // N*CP
    float*          st  = (float*)(Gb + (size_t)N_ * CP);      // N*2

    // zero dx for split-K atomic accumulation
    hipMemsetAsync(dx, 0, (size_t)N_ * D_ * sizeof(float), stream);

    k_convert_x<<<(N_ * D_ / 4) / 256, 256, 0, stream>>>(x, xb);
    k_convert_w<<<dim3(CP / 64, D_ / 64), 256, 0, stream>>>(W, Wb, WbT);

    // GEMM1: logits[n,c] = sum_d xb[n,d]*WbT[c,d] + b[c]   (M=2048, N=CP, K=2048)
    k_gemm_bt<<<dim3(16, CP / 128, 1), 256, 0, stream>>>(
        xb, WbT, logits, b, D_, D_, C_, C_, D_ / 32, D_ / 32, 0);

    k_rowstats<<<N_, 256, 0, stream>>>(logits, y, st);
    k_gmat<<<(N_ * (CP / 4)) / 256, 256, 0, stream>>>(logits, y, st, Gb);

    // GEMM2: dx[n,d] = sum_c Gb[n,c]*Wb[d,c]   (M=2048, N=2048, K=CP), split-K x4
    k_gemm_bt<<<dim3(16, D_ / 128, 4), 256, 0, stream>>>(
        Gb, Wb, dx, nullptr, CP, CP, D_, D_, CP / 32, (CP / 32) / 4, 1);
}